// Round 1
// baseline (217.340 us; speedup 1.0000x reference)
//
#include <hip/hip_runtime.h>
#include <hip/hip_bf16.h>

#define LOG2PI 1.8378770664093453f

// Problem sizes (fixed): N=16384 rows, M=4096, K=64.
// GEMM output columns: 0-63 z_mu, 64-127 c = x@Wd^T, 128 s_enc dot, 129 x.b_dec,
// 130 sum(x^2) [written by staging path], 131-143 zero pad. Stride 144.

typedef __attribute__((ext_vector_type(8))) short bf16x8;
typedef __attribute__((ext_vector_type(4))) float f32x4;

__device__ __forceinline__ unsigned short f2bf(float f) {
    unsigned int u = __builtin_bit_cast(unsigned int, f);
    u += 0x7FFFu + ((u >> 16) & 1u);   // RNE to bf16
    return (unsigned short)(u >> 16);
}

// ---------------- pack B: Bp[c][j] (bf16), c in [0,144), j in [0,4096)
__global__ void pack_b_kernel(const float* __restrict__ We,   // [4096][64]
                              const float* __restrict__ Wes,  // [4096]
                              const float* __restrict__ Wd,   // [64][4096]
                              const float* __restrict__ bd,   // [4096]
                              unsigned short* __restrict__ Bp) {
    int c = blockIdx.x;
    int j = blockIdx.y * 256 + threadIdx.x;
    float v = 0.0f;
    if (c < 64)        v = We[j * 64 + c];
    else if (c < 128)  v = Wd[(c - 64) * 4096 + j];
    else if (c == 128) v = Wes[j];
    else if (c == 129) v = bd[j];
    Bp[c * 4096 + j] = f2bf(v);
}

// ---------------- G = Wd Wd^T [64][64], h = Wd @ bd [64], e = sum(bd^2)
__global__ void prep_g_kernel(const float* __restrict__ Wd, const float* __restrict__ bd,
                              float* __restrict__ G, float* __restrict__ hv,
                              float* __restrict__ ev) {
    __shared__ float red[256];
    int a = blockIdx.x, t = threadIdx.x;
    int col = t & 63, seg = t >> 6;
    const float* ra = Wd + a * 4096;
    const float* rc = Wd + col * 4096;
    float p = 0.f;
    int j0 = seg * 1024;
    for (int j = 0; j < 1024; ++j) p = fmaf(ra[j0 + j], rc[j0 + j], p);
    red[t] = p;
    __syncthreads();
    if (t < 64) G[a * 64 + t] = red[t] + red[t + 64] + red[t + 128] + red[t + 192];
    __syncthreads();
    float ph = 0.f;
    for (int j = t; j < 4096; j += 256) ph = fmaf(ra[j], bd[j], ph);
    red[t] = ph;
    __syncthreads();
    for (int s = 128; s > 0; s >>= 1) { if (t < s) red[t] += red[t + s]; __syncthreads(); }
    if (t == 0) hv[a] = red[0];
    if (a == 0) {   // uniform branch per block -> barriers legal
        __syncthreads();
        float pe = 0.f;
        for (int j = t; j < 4096; j += 256) { float b = bd[j]; pe = fmaf(b, b, pe); }
        red[t] = pe;
        __syncthreads();
        for (int s = 128; s > 0; s >>= 1) { if (t < s) red[t] += red[t + s]; __syncthreads(); }
        if (t == 0) ev[0] = red[0];
    }
}

// ---------------- main GEMM: Out[16384][144] = bf16(x) @ bf16(Bcat), + sx2 col
#define GT 384
__global__ __launch_bounds__(GT) void gemm_kernel(const float* __restrict__ x,
                                                  const unsigned short* __restrict__ Bp,
                                                  float* __restrict__ OutW) {
    // A tile [64 rows][64 k] bf16 = 8192 B, B tile [144 cols][64 k] bf16 = 18432 B
    __shared__ char lds[64 * 128 + 144 * 128];
    const int tid = threadIdx.x;
    const int rowbase = blockIdx.x * 64;
    const int wid = tid >> 6, lane = tid & 63;
    const int wm = wid / 3, wn = wid % 3;     // 6 waves = 2 (m) x 3 (n)
    const int l15 = lane & 15, lhi = lane >> 4;

    f32x4 acc[2][3];
#pragma unroll
    for (int mi = 0; mi < 2; ++mi)
#pragma unroll
        for (int ni = 0; ni < 3; ++ni) acc[mi][ni] = (f32x4){0.f, 0.f, 0.f, 0.f};

    float sxa0 = 0.f, sxa1 = 0.f, sxa2 = 0.f;

    for (int kt = 0; kt < 64; ++kt) {
        // stage A: 64x64 fp32 -> bf16, u=row*16+f4col
#pragma unroll
        for (int i = 0; i < 3; ++i) {
            int u = tid + GT * i;
            if (u < 1024) {
                int r = u >> 4, fc = u & 15;
                const float4 v = *reinterpret_cast<const float4*>(
                    x + (size_t)(rowbase + r) * 4096 + kt * 64 + fc * 4);
                float ss = v.x * v.x + v.y * v.y + v.z * v.z + v.w * v.w;
                if (i == 0) sxa0 += ss; else if (i == 1) sxa1 += ss; else sxa2 += ss;
                unsigned int lo = (unsigned int)f2bf(v.x) | ((unsigned int)f2bf(v.y) << 16);
                unsigned int hi = (unsigned int)f2bf(v.z) | ((unsigned int)f2bf(v.w) << 16);
                int boff = (r * 128 + fc * 8) ^ ((r & 7) << 4);   // XOR swizzle (G4)
                *reinterpret_cast<uint2*>(lds + boff) = make_uint2(lo, hi);
            }
        }
        // stage B: 144 rows x 128 B, 1152 x 16 B chunks = GT*3 exactly
#pragma unroll
        for (int i = 0; i < 3; ++i) {
            int u = tid + GT * i;
            int c = u >> 3, sub = u & 7;
            uint4 v = *reinterpret_cast<const uint4*>(
                reinterpret_cast<const char*>(Bp) + (size_t)c * 8192 + kt * 128 + sub * 16);
            int boff = 8192 + ((c * 128 + sub * 16) ^ ((c & 7) << 4));
            *reinterpret_cast<uint4*>(lds + boff) = v;
        }
        __syncthreads();
#pragma unroll
        for (int kk = 0; kk < 2; ++kk) {
            bf16x8 am[2], bn[3];
#pragma unroll
            for (int mi = 0; mi < 2; ++mi) {
                int r = wm * 32 + mi * 16 + l15;
                int boff = (r * 128 + kk * 64 + lhi * 16) ^ ((r & 7) << 4);
                am[mi] = *reinterpret_cast<bf16x8*>(lds + boff);
            }
#pragma unroll
            for (int ni = 0; ni < 3; ++ni) {
                int c = (wn * 3 + ni) * 16 + l15;
                int boff = 8192 + ((c * 128 + kk * 64 + lhi * 16) ^ ((c & 7) << 4));
                bn[ni] = *reinterpret_cast<bf16x8*>(lds + boff);
            }
#pragma unroll
            for (int mi = 0; mi < 2; ++mi)
#pragma unroll
                for (int ni = 0; ni < 3; ++ni)
                    acc[mi][ni] = __builtin_amdgcn_mfma_f32_16x16x32_bf16(
                        am[mi], bn[ni], acc[mi][ni], 0, 0, 0);
        }
        __syncthreads();
    }

    // C store: D row=(lane>>4)*4+i, col=lane&15 (m89-verified layout)
#pragma unroll
    for (int mi = 0; mi < 2; ++mi)
#pragma unroll
        for (int ni = 0; ni < 3; ++ni) {
            int nf = wn * 3 + ni;
#pragma unroll
            for (int i2 = 0; i2 < 4; ++i2) {
                int row = rowbase + wm * 32 + mi * 16 + lhi * 4 + i2;
                int col = nf * 16 + l15;
                if (col < 130) OutW[(size_t)row * 144 + col] = acc[mi][ni][i2];
            }
        }

    // sx2: each 16-lane f4-group owns one row; reduce and store to col 130
#pragma unroll
    for (int i = 0; i < 3; ++i) {
        int u = tid + GT * i;
        float s = (i == 0) ? sxa0 : (i == 1) ? sxa1 : sxa2;
        s += __shfl_xor(s, 1); s += __shfl_xor(s, 2);
        s += __shfl_xor(s, 4); s += __shfl_xor(s, 8);
        if (u < 1024 && (u & 15) == 0)
            OutW[(size_t)(rowbase + (u >> 4)) * 144 + 130] = s;
    }
}

// ---------------- phase 2: one wave per row, K=64 = 64 lanes
__global__ __launch_bounds__(256) void phase2_kernel(const float* __restrict__ OutW,
        const float* __restrict__ noise, const float* __restrict__ bem,
        const float* __restrict__ Wds, const float* __restrict__ bes_p,
        const float* __restrict__ bds_p, const float* __restrict__ G,
        const float* __restrict__ hv, const float* __restrict__ ev,
        float* __restrict__ partial) {
    __shared__ float Gl[4096];
    __shared__ float hl[64], wl[64], beml[64];
    __shared__ float red[4];
    int tid = threadIdx.x;
    for (int i = tid; i < 4096; i += 256) Gl[i] = G[i];
    if (tid < 64) { hl[tid] = hv[tid]; wl[tid] = Wds[tid]; beml[tid] = bem[tid]; }
    __syncthreads();
    float bes = bes_p[0], bds = bds_p[0], e = ev[0];
    int wid = tid >> 6, k = tid & 63;
    float wacc = 0.f;
    for (int rr = 0; rr < 16; ++rr) {
        int row = blockIdx.x * 64 + wid * 16 + rr;
        const float* orow = OutW + (size_t)row * 144;
        float zmu = orow[k] + beml[k];
        float ck  = orow[64 + k];
        float se  = orow[128] + bes;
        float dd  = orow[129];
        float sx2 = orow[130];
        float nz  = noise[(size_t)row * 64 + k];
        float s2 = se * se;
        float z = fmaf(s2, nz, zmu);
        // t_k = (G z)_k using symmetry: coalesced/conflict-free column read
        float t = 0.f;
#pragma unroll 16
        for (int kp = 0; kp < 64; ++kp)
            t = fmaf(Gl[kp * 64 + k], __shfl(z, kp), t);
        float ra = z * z;                 // prior
        float rb = nz * nz;               // noise^2 (= sq_post/var_z)
        float rc = z * wl[k];             // s_dec dot
        float rd = z * ck;                // x . x_mu
        float re = z * fmaf(2.f, hl[k], t); // z^T G z + 2 z.h
#pragma unroll
        for (int d = 1; d < 64; d <<= 1) {
            ra += __shfl_xor(ra, d); rb += __shfl_xor(rb, d);
            rc += __shfl_xor(rc, d); rd += __shfl_xor(rd, d);
            re += __shfl_xor(re, d);
        }
        float sdec = rc + bds;
        float xxmu = rd + dd;
        float xmu2 = re + e;
        float sq_lik = sx2 - 2.f * xxmu + xmu2;
        float vz = s2 * s2;
        float sd2 = sdec * sdec;
        float vx = sd2 * sd2;
        wacc += 0.5f * (4096.f * LOG2PI + 4096.f * __logf(vx) + sq_lik / vx
                        + ra - 64.f * __logf(vz) - rb);
    }
    if (k == 0) red[wid] = wacc;
    __syncthreads();
    if (tid == 0) partial[blockIdx.x] = red[0] + red[1] + red[2] + red[3];
}

__global__ __launch_bounds__(256) void final_reduce_kernel(const float* __restrict__ partial,
                                                           float* __restrict__ out) {
    __shared__ float red[4];
    int tid = threadIdx.x;
    float v = partial[tid];
#pragma unroll
    for (int d = 1; d < 64; d <<= 1) v += __shfl_xor(v, d);
    if ((tid & 63) == 0) red[tid >> 6] = v;
    __syncthreads();
    if (tid == 0) out[0] = red[0] + red[1] + red[2] + red[3];
}

extern "C" void kernel_launch(void* const* d_in, const int* in_sizes, int n_in,
                              void* d_out, int out_size, void* d_ws, size_t ws_size,
                              hipStream_t stream) {
    const float* x     = (const float*)d_in[0];
    const float* noise = (const float*)d_in[1];
    const float* We    = (const float*)d_in[2];
    const float* bem   = (const float*)d_in[3];
    const float* Wes   = (const float*)d_in[4];
    const float* bes   = (const float*)d_in[5];
    const float* Wd    = (const float*)d_in[6];
    const float* bdm   = (const float*)d_in[7];
    const float* Wds   = (const float*)d_in[8];
    const float* bds   = (const float*)d_in[9];

    char* ws = (char*)d_ws;
    float* OutW          = (float*)ws;                    // 16384*144*4 = 9437184 B
    unsigned short* Bp   = (unsigned short*)(ws + 9437184); // 144*4096*2 = 1179648 B
    float* G             = (float*)(ws + 10616832);       // 16384 B
    float* hv            = (float*)(ws + 10633216);       // 256 B
    float* ev            = (float*)(ws + 10633472);       // 256 B
    float* partial       = (float*)(ws + 10633728);       // 1024 B

    pack_b_kernel<<<dim3(144, 16), 256, 0, stream>>>(We, Wes, Wd, bdm, Bp);
    prep_g_kernel<<<64, 256, 0, stream>>>(Wd, bdm, G, hv, ev);
    gemm_kernel<<<256, GT, 0, stream>>>(x, Bp, OutW);
    phase2_kernel<<<256, 256, 0, stream>>>(OutW, noise, bem, Wds, bes, bds, G, hv, ev, partial);
    final_reduce_kernel<<<1, 256, 0, stream>>>(partial, (float*)d_out);
}

// Round 2
// 173.953 us; speedup vs baseline: 1.2494x; 1.2494x over previous
//
#include <hip/hip_runtime.h>
#include <hip/hip_bf16.h>

#define LOG2PI 1.8378770664093453f

// N=16384, M=4096, K=64.
// OutW columns: 0-63 z_mu(dot), 64-127 c = x@Wd^T, 128 s_enc dot, 129 x.b_dec,
// 130 sum(x^2), 131-143 pad. Stride 144.
//
// Bp packed layout (bf16): chunk index (kq*144 + c), kq = kt*4+kb (kt: 32-wide
// k-step, kb: 8-wide sub-group), each chunk = 8 bf16 = Bcat[col c][k=kq*8 .. +8].
// A lane (l15=lane&15, kg=lane>>4) loading frag ni reads chunk (kt*4+kg)*144 + ni*16 + l15
// => 16 consecutive chunks per 16-lane group = 256 B coalesced.

typedef __attribute__((ext_vector_type(8))) short bf16x8;
typedef __attribute__((ext_vector_type(4))) float f32x4;

__device__ __forceinline__ unsigned short f2bf(float f) {
    unsigned int u = __builtin_bit_cast(unsigned int, f);
    u += 0x7FFFu + ((u >> 16) & 1u);   // RNE
    return (unsigned short)(u >> 16);
}

// ---------------- pack B into MFMA-fragment-ordered bf16 chunks
__global__ __launch_bounds__(256) void pack_b_kernel(const float* __restrict__ We,
        const float* __restrict__ Wes, const float* __restrict__ Wd,
        const float* __restrict__ bd, unsigned short* __restrict__ Bp) {
    int idx = blockIdx.x * 256 + threadIdx.x;   // 0 .. 73727  == kq*144 + c
    int c = idx % 144;
    int kq = idx / 144;                         // 0..511
    int k0 = kq * 8;
    unsigned short out[8];
#pragma unroll
    for (int j = 0; j < 8; ++j) {
        int m = k0 + j;
        float v = 0.f;
        if (c < 64)        v = We[(size_t)m * 64 + c];
        else if (c < 128)  v = Wd[(size_t)(c - 64) * 4096 + m];
        else if (c == 128) v = Wes[m];
        else if (c == 129) v = bd[m];
        out[j] = f2bf(v);
    }
    *reinterpret_cast<uint4*>(Bp + (size_t)idx * 8) = *reinterpret_cast<uint4*>(out);
}

// ---------------- G = Wd Wd^T [64][64], h = Wd @ bd [64], e = sum(bd^2)
__global__ void prep_g_kernel(const float* __restrict__ Wd, const float* __restrict__ bd,
                              float* __restrict__ G, float* __restrict__ hv,
                              float* __restrict__ ev) {
    __shared__ float red[256];
    int a = blockIdx.x, t = threadIdx.x;
    int col = t & 63, seg = t >> 6;
    const float* ra = Wd + (size_t)a * 4096;
    const float* rc = Wd + (size_t)col * 4096;
    float p = 0.f;
    int j0 = seg * 1024;
    for (int j = 0; j < 1024; ++j) p = fmaf(ra[j0 + j], rc[j0 + j], p);
    red[t] = p;
    __syncthreads();
    if (t < 64) G[a * 64 + t] = red[t] + red[t + 64] + red[t + 128] + red[t + 192];
    __syncthreads();
    float ph = 0.f;
    for (int j = t; j < 4096; j += 256) ph = fmaf(ra[j], bd[j], ph);
    red[t] = ph;
    __syncthreads();
    for (int s = 128; s > 0; s >>= 1) { if (t < s) red[t] += red[t + s]; __syncthreads(); }
    if (t == 0) hv[a] = red[0];
    if (a == 0) {
        __syncthreads();
        float pe = 0.f;
        for (int j = t; j < 4096; j += 256) { float b = bd[j]; pe = fmaf(b, b, pe); }
        red[t] = pe;
        __syncthreads();
        for (int s = 128; s > 0; s >>= 1) { if (t < s) red[t] += red[t + s]; __syncthreads(); }
        if (t == 0) ev[0] = red[0];
    }
}

// ---------------- main GEMM: barrier-free single-wave blocks, all-register
__global__ __launch_bounds__(64) void gemm_kernel(const float* __restrict__ x,
        const unsigned short* __restrict__ Bp, float* __restrict__ OutW) {
    const int lane = threadIdx.x;
    const int l15 = lane & 15, kg = lane >> 4;
    const int rowbase = blockIdx.x * 16;

    const float4* xa = reinterpret_cast<const float4*>(
        x + (size_t)(rowbase + l15) * 4096 + kg * 8);
    const bf16x8* bch = reinterpret_cast<const bf16x8*>(Bp);

    f32x4 acc[9];
#pragma unroll
    for (int i = 0; i < 9; ++i) acc[i] = (f32x4){0.f, 0.f, 0.f, 0.f};
    float sx2 = 0.f;

    float4 a0[2], a1[2];
    bf16x8 b0[9], b1[9];

#define LDA(kt, d) do { d[0] = xa[(kt) * 8]; d[1] = xa[(kt) * 8 + 1]; } while (0)
#define LDB(kt, d) do { \
        const bf16x8* p_ = bch + ((size_t)((kt) * 4 + kg) * 144 + l15); \
        _Pragma("unroll") \
        for (int ni_ = 0; ni_ < 9; ++ni_) d[ni_] = p_[ni_ * 16]; \
    } while (0)
#define STEP(a, b) do { \
        float f_[8] = {a[0].x, a[0].y, a[0].z, a[0].w, a[1].x, a[1].y, a[1].z, a[1].w}; \
        bf16x8 af_; \
        _Pragma("unroll") \
        for (int j_ = 0; j_ < 8; ++j_) { \
            af_[j_] = (short)f2bf(f_[j_]); \
            sx2 = fmaf(f_[j_], f_[j_], sx2); \
        } \
        _Pragma("unroll") \
        for (int ni_ = 0; ni_ < 9; ++ni_) \
            acc[ni_] = __builtin_amdgcn_mfma_f32_16x16x32_bf16(af_, b[ni_], acc[ni_], 0, 0, 0); \
    } while (0)

    LDA(0, a0); LDB(0, b0);
    LDA(1, a1); LDB(1, b1);
    for (int kt = 0; kt < 124; kt += 2) {
        STEP(a0, b0); LDA(kt + 2, a0); LDB(kt + 2, b0);
        STEP(a1, b1); LDA(kt + 3, a1); LDB(kt + 3, b1);
    }
    STEP(a0, b0); LDA(126, a0); LDB(126, b0);
    STEP(a1, b1); LDA(127, a1); LDB(127, b1);
    STEP(a0, b0);
    STEP(a1, b1);
#undef LDA
#undef LDB
#undef STEP

    // C layout: col = lane&15, row = (lane>>4)*4 + i  (m89-verified)
#pragma unroll
    for (int ni = 0; ni < 9; ++ni) {
        int col = ni * 16 + l15;
        if (col < 130) {
#pragma unroll
            for (int i = 0; i < 4; ++i)
                OutW[(size_t)(rowbase + kg * 4 + i) * 144 + col] = acc[ni][i];
        }
    }
    // sum(x^2): reduce across the 4 k-groups holding the same row
    sx2 += __shfl_xor(sx2, 16);
    sx2 += __shfl_xor(sx2, 32);
    if (lane < 16) OutW[(size_t)(rowbase + lane) * 144 + 130] = sx2;
}

// ---------------- phase 2: one wave per row (x2), K=64 = 64 lanes
__global__ __launch_bounds__(256) void phase2_kernel(const float* __restrict__ OutW,
        const float* __restrict__ noise, const float* __restrict__ bem,
        const float* __restrict__ Wds, const float* __restrict__ bes_p,
        const float* __restrict__ bds_p, const float* __restrict__ G,
        const float* __restrict__ hv, const float* __restrict__ ev,
        float* __restrict__ partial) {
    __shared__ float Gl[4096];
    __shared__ float hl[64], wl[64], beml[64];
    __shared__ float red[4];
    int tid = threadIdx.x;
    for (int i = tid; i < 4096; i += 256) Gl[i] = G[i];
    if (tid < 64) { hl[tid] = hv[tid]; wl[tid] = Wds[tid]; beml[tid] = bem[tid]; }
    __syncthreads();
    float bes = bes_p[0], bds = bds_p[0], e = ev[0];
    int wid = tid >> 6, k = tid & 63;
    float wacc = 0.f;
#pragma unroll
    for (int rr = 0; rr < 2; ++rr) {
        int row = blockIdx.x * 8 + wid * 2 + rr;
        const float* orow = OutW + (size_t)row * 144;
        float zmu = orow[k] + beml[k];
        float ck  = orow[64 + k];
        float se  = orow[128] + bes;
        float dd  = orow[129];
        float sx2 = orow[130];
        float nz  = noise[(size_t)row * 64 + k];
        float s2 = se * se;
        float z = fmaf(s2, nz, zmu);
        // t_k = (G z)_k via symmetry; 4-way split dependency chain
        float t0 = 0.f, t1 = 0.f, t2 = 0.f, t3 = 0.f;
#pragma unroll
        for (int kp = 0; kp < 64; kp += 4) {
            t0 = fmaf(Gl[(kp + 0) * 64 + k], __shfl(z, kp + 0), t0);
            t1 = fmaf(Gl[(kp + 1) * 64 + k], __shfl(z, kp + 1), t1);
            t2 = fmaf(Gl[(kp + 2) * 64 + k], __shfl(z, kp + 2), t2);
            t3 = fmaf(Gl[(kp + 3) * 64 + k], __shfl(z, kp + 3), t3);
        }
        float t = (t0 + t1) + (t2 + t3);
        float ra = z * z;
        float rb = nz * nz;
        float rc = z * wl[k];
        float rd = z * ck;
        float re = z * fmaf(2.f, hl[k], t);
#pragma unroll
        for (int d = 1; d < 64; d <<= 1) {
            ra += __shfl_xor(ra, d); rb += __shfl_xor(rb, d);
            rc += __shfl_xor(rc, d); rd += __shfl_xor(rd, d);
            re += __shfl_xor(re, d);
        }
        float sdec = rc + bds;
        float xxmu = rd + dd;
        float xmu2 = re + e;
        float sq_lik = sx2 - 2.f * xxmu + xmu2;
        float vz = s2 * s2;
        float sd2 = sdec * sdec;
        float vx = sd2 * sd2;
        wacc += 0.5f * (4096.f * LOG2PI + 4096.f * __logf(vx) + sq_lik / vx
                        + ra - 64.f * __logf(vz) - rb);
    }
    if (k == 0) red[wid] = wacc;
    __syncthreads();
    if (tid == 0) partial[blockIdx.x] = red[0] + red[1] + red[2] + red[3];
}

__global__ __launch_bounds__(256) void final_reduce_kernel(const float* __restrict__ partial,
                                                           float* __restrict__ out) {
    __shared__ float red[4];
    int tid = threadIdx.x;
    float v = 0.f;
    for (int i = tid; i < 2048; i += 256) v += partial[i];
#pragma unroll
    for (int d = 1; d < 64; d <<= 1) v += __shfl_xor(v, d);
    if ((tid & 63) == 0) red[tid >> 6] = v;
    __syncthreads();
    if (tid == 0) out[0] = red[0] + red[1] + red[2] + red[3];
}

extern "C" void kernel_launch(void* const* d_in, const int* in_sizes, int n_in,
                              void* d_out, int out_size, void* d_ws, size_t ws_size,
                              hipStream_t stream) {
    const float* x     = (const float*)d_in[0];
    const float* noise = (const float*)d_in[1];
    const float* We    = (const float*)d_in[2];
    const float* bem   = (const float*)d_in[3];
    const float* Wes   = (const float*)d_in[4];
    const float* bes   = (const float*)d_in[5];
    const float* Wd    = (const float*)d_in[6];
    const float* bdm   = (const float*)d_in[7];
    const float* Wds   = (const float*)d_in[8];
    const float* bds   = (const float*)d_in[9];

    char* ws = (char*)d_ws;
    float* OutW          = (float*)ws;                      // 9,437,184 B
    unsigned short* Bp   = (unsigned short*)(ws + 9437184); // 1,179,648 B
    float* G             = (float*)(ws + 10616832);         // 16,384 B
    float* hv            = (float*)(ws + 10633216);
    float* ev            = (float*)(ws + 10633472);
    float* partial       = (float*)(ws + 10633728);         // 8,192 B

    pack_b_kernel<<<288, 256, 0, stream>>>(We, Wes, Wd, bdm, Bp);
    prep_g_kernel<<<64, 256, 0, stream>>>(Wd, bdm, G, hv, ev);
    gemm_kernel<<<1024, 64, 0, stream>>>(x, Bp, OutW);
    phase2_kernel<<<2048, 256, 0, stream>>>(OutW, noise, bem, Wds, bes, bds, G, hv, ev, partial);
    final_reduce_kernel<<<1, 256, 0, stream>>>(partial, (float*)d_out);
}